// Round 2
// baseline (749.707 us; speedup 1.0000x reference)
//
#include <hip/hip_runtime.h>
#include <hip/hip_bf16.h>

#define DEVINL __device__ __forceinline__

DEVINL int clampidx(int v, int n) { return ((unsigned)v < (unsigned)n) ? v : 0; }
DEVINL float bflo(unsigned int u) { return __uint_as_float(u << 16); }
DEVINL float bfhi(unsigned int u) { return __uint_as_float(u & 0xffff0000u); }
// f32 -> bf16 round-to-nearest-even (finite inputs only)
DEVINL unsigned int f2bf(float f) {
    unsigned int u = __float_as_uint(f);
    u += 0x7fffu + ((u >> 16) & 1u);
    return u >> 16;
}

// ===========================================================================
// CSR build via bucket counting sort. Buckets = dst>>7 (128 nodes each).
// packed edge word: (dstLocal[7b] << 25) | src[25b]   (n < 2^25)
// ===========================================================================
__global__ __launch_bounds__(256) void k_bktcount(const int* __restrict__ ei,
                                                  int* __restrict__ bktCnt, int E, int n) {
    __shared__ int hist[1024];
    for (int i = threadIdx.x; i < 1024; i += 256) hist[i] = 0;
    __syncthreads();
    const int base = blockIdx.x * 4096;
#pragma unroll
    for (int j = 0; j < 16; ++j) {
        int i = base + j * 256 + threadIdx.x;
        if (i < E) atomicAdd(&hist[clampidx(ei[(size_t)E + i], n) >> 7], 1);
    }
    __syncthreads();
    for (int b = threadIdx.x; b < 1024; b += 256) {
        int c = hist[b];
        if (c) atomicAdd(&bktCnt[b], c);
    }
}

__global__ __launch_bounds__(256) void k_bktscan(const int* __restrict__ bktCnt,
                                                 int* __restrict__ bktBase,
                                                 int* __restrict__ bktCur, int NB) {
    __shared__ int sh[256];
    int carry = 0;
    for (int c0 = 0; c0 < NB; c0 += 256) {
        const int i = c0 + threadIdx.x;
        const int v = (i < NB) ? bktCnt[i] : 0;
        sh[threadIdx.x] = v;
        __syncthreads();
        for (int off = 1; off < 256; off <<= 1) {
            int t = (threadIdx.x >= off) ? sh[threadIdx.x - off] : 0;
            __syncthreads();
            sh[threadIdx.x] += t;
            __syncthreads();
        }
        if (i < NB) {
            const int excl = carry + sh[threadIdx.x] - v;
            bktBase[i] = excl;
            bktCur[i] = excl;
        }
        const int tot = sh[255];
        __syncthreads();
        carry += tot;
    }
    if (threadIdx.x == 0) bktBase[NB] = carry;
}

__global__ __launch_bounds__(256) void k_bktscatter(const int* __restrict__ ei,
                                                    int* __restrict__ bktCur,
                                                    unsigned int* __restrict__ packed,
                                                    int E, int n) {
    __shared__ unsigned int sPack[4096];
    __shared__ unsigned short sBkt[4096];
    __shared__ int sHist[1024], sStart[1024], sLoc[1024];
    for (int i = threadIdx.x; i < 1024; i += 256) {
        sHist[i] = 0;
        sLoc[i] = 0;
    }
    __syncthreads();
    const int base = blockIdx.x * 4096;
#pragma unroll
    for (int j = 0; j < 16; ++j) {
        const int k = j * 256 + threadIdx.x;
        const int i = base + k;
        if (i < E) {
            const int s = clampidx(ei[i], n);
            const int d = clampidx(ei[(size_t)E + i], n);
            const int b = d >> 7;
            sPack[k] = ((unsigned)(d & 127) << 25) | (unsigned)s;
            sBkt[k] = (unsigned short)b;
            atomicAdd(&sHist[b], 1);
        }
    }
    __syncthreads();
    for (int b = threadIdx.x; b < 1024; b += 256) {
        const int c = sHist[b];
        sStart[b] = c ? atomicAdd(&bktCur[b], c) : 0;
    }
    __syncthreads();
#pragma unroll
    for (int j = 0; j < 16; ++j) {
        const int k = j * 256 + threadIdx.x;
        const int i = base + k;
        if (i < E) {
            const int b = sBkt[k];
            const int pos = sStart[b] + atomicAdd(&sLoc[b], 1);
            packed[pos] = sPack[k];
        }
    }
}

__global__ __launch_bounds__(256) void k_bktfill(const unsigned int* __restrict__ packed,
                                                 const int* __restrict__ bktBase,
                                                 int* __restrict__ p, float* __restrict__ dinv,
                                                 int* __restrict__ srcs, int n) {
    constexpr int CAP = 8192;
    __shared__ unsigned int sPack[CAP];
    __shared__ int sSrc[CAP];
    __shared__ int deg[128], incl[128], cur[128];
    const int bkt = blockIdx.x;
    const int e0 = bktBase[bkt], e1 = bktBase[bkt + 1];
    const int cnt = e1 - e0;
    const int tid = threadIdx.x;
    if (tid < 128) deg[tid] = 0;
    __syncthreads();
    for (int i = tid; i < cnt; i += 256) {
        const unsigned int u = packed[e0 + i];
        if (i < CAP) sPack[i] = u;
        atomicAdd(&deg[u >> 25], 1);
    }
    __syncthreads();
    if (tid < 128) incl[tid] = deg[tid];
    __syncthreads();
    for (int off = 1; off < 128; off <<= 1) {
        const int v = (tid < 128 && tid >= off) ? incl[tid - off] : 0;
        __syncthreads();
        if (tid < 128) incl[tid] += v;
        __syncthreads();
    }
    const int node0 = bkt << 7;
    if (tid < 128) {
        cur[tid] = incl[tid] - deg[tid];
        const int node = node0 + tid;
        if (node < n) {
            p[node] = e0 + incl[tid];
            dinv[node] = rsqrtf((float)deg[tid] + 1.0f);
        }
    }
    __syncthreads();
    for (int i = tid; i < cnt; i += 256) {
        const unsigned int u = (i < CAP) ? sPack[i] : packed[e0 + i];
        const int dl = (int)(u >> 25);
        const int s = (int)(u & 0x1FFFFFFu);
        const int pos = atomicAdd(&cur[dl], 1);
        if (pos < CAP) sSrc[pos] = s;
        else srcs[e0 + pos] = s;
    }
    __syncthreads();
    const int lim = cnt < CAP ? cnt : CAP;
    for (int i = tid; i < lim; i += 256) srcs[e0 + i] = sSrc[i];
}

// ===========================================================================
// Register-tiled GEMM: Y(bf16 pairs)[n, BCOLS] = X[n,128] @ W[128, BCOLS]
// 256 threads; each computes a 4-row x 8-col register tile.
// ===========================================================================
template <int BCOLS, bool IN_BF16>
__global__ __launch_bounds__(256) void k_gemm_rt(const void* __restrict__ Xv,
                                                 const float* __restrict__ W,
                                                 unsigned int* __restrict__ Y, int ystrideU,
                                                 int n) {
    constexpr int KC = 32;
    constexpr int CG = BCOLS / 8;
    constexpr int RG = 256 / CG;
    constexpr int BROWS = RG * 4;
    constexpr int P = BROWS + 4;
    __shared__ float Ws[KC * BCOLS];
    __shared__ float xs[KC * P];

    const int tid = threadIdx.x;
    const int row0 = blockIdx.x * BROWS;
    const int ct = tid % CG;
    const int rt = tid / CG;

    float acc[4][8];
#pragma unroll
    for (int i = 0; i < 4; ++i)
#pragma unroll
        for (int j = 0; j < 8; ++j) acc[i][j] = 0.0f;

    for (int k0 = 0; k0 < 128; k0 += KC) {
        __syncthreads();
        for (int idx = tid * 4; idx < KC * BCOLS; idx += 1024)
            *(float4*)&Ws[idx] = *(const float4*)&W[(size_t)k0 * BCOLS + idx];
        if (IN_BF16) {
            const int row = tid >> 1, q = tid & 1;
            const int grow = row0 + row;
            const unsigned int* src =
                (const unsigned int*)Xv + (size_t)grow * 64 + (k0 >> 1) + q * 8;
            uint4 u0 = make_uint4(0, 0, 0, 0), u1 = make_uint4(0, 0, 0, 0);
            if (grow < n) {
                u0 = *(const uint4*)src;
                u1 = *(const uint4*)(src + 4);
            }
            const int kb = q * 16;
            float* xp = &xs[row];
            xp[(kb + 0) * P] = bflo(u0.x); xp[(kb + 1) * P] = bfhi(u0.x);
            xp[(kb + 2) * P] = bflo(u0.y); xp[(kb + 3) * P] = bfhi(u0.y);
            xp[(kb + 4) * P] = bflo(u0.z); xp[(kb + 5) * P] = bfhi(u0.z);
            xp[(kb + 6) * P] = bflo(u0.w); xp[(kb + 7) * P] = bfhi(u0.w);
            xp[(kb + 8) * P] = bflo(u1.x); xp[(kb + 9) * P] = bfhi(u1.x);
            xp[(kb + 10) * P] = bflo(u1.y); xp[(kb + 11) * P] = bfhi(u1.y);
            xp[(kb + 12) * P] = bflo(u1.z); xp[(kb + 13) * P] = bfhi(u1.z);
            xp[(kb + 14) * P] = bflo(u1.w); xp[(kb + 15) * P] = bfhi(u1.w);
        } else {
            const int row = tid >> 2, q = tid & 3;
            const int grow = row0 + row;
            const float* src = (const float*)Xv + (size_t)grow * 128 + k0 + q * 8;
            float4 v0 = make_float4(0, 0, 0, 0), v1 = make_float4(0, 0, 0, 0);
            if (grow < n) {
                v0 = *(const float4*)src;
                v1 = *(const float4*)(src + 4);
            }
            const int kb = q * 8;
            float* xp = &xs[row];
            xp[(kb + 0) * P] = v0.x; xp[(kb + 1) * P] = v0.y;
            xp[(kb + 2) * P] = v0.z; xp[(kb + 3) * P] = v0.w;
            xp[(kb + 4) * P] = v1.x; xp[(kb + 5) * P] = v1.y;
            xp[(kb + 6) * P] = v1.z; xp[(kb + 7) * P] = v1.w;
        }
        __syncthreads();

#pragma unroll 8
        for (int k = 0; k < KC; ++k) {
            const float4 xv = *(const float4*)&xs[k * P + rt * 4];
            const float4 wA = *(const float4*)&Ws[k * BCOLS + ct * 8];
            const float4 wB = *(const float4*)&Ws[k * BCOLS + ct * 8 + 4];
            const float xr[4] = {xv.x, xv.y, xv.z, xv.w};
#pragma unroll
            for (int i = 0; i < 4; ++i) {
                acc[i][0] = fmaf(xr[i], wA.x, acc[i][0]);
                acc[i][1] = fmaf(xr[i], wA.y, acc[i][1]);
                acc[i][2] = fmaf(xr[i], wA.z, acc[i][2]);
                acc[i][3] = fmaf(xr[i], wA.w, acc[i][3]);
                acc[i][4] = fmaf(xr[i], wB.x, acc[i][4]);
                acc[i][5] = fmaf(xr[i], wB.y, acc[i][5]);
                acc[i][6] = fmaf(xr[i], wB.z, acc[i][6]);
                acc[i][7] = fmaf(xr[i], wB.w, acc[i][7]);
            }
        }
    }

#pragma unroll
    for (int i = 0; i < 4; ++i) {
        const int row = row0 + rt * 4 + i;
        if (row < n) {
            uint4 o;
            o.x = f2bf(acc[i][0]) | (f2bf(acc[i][1]) << 16);
            o.y = f2bf(acc[i][2]) | (f2bf(acc[i][3]) << 16);
            o.z = f2bf(acc[i][4]) | (f2bf(acc[i][5]) << 16);
            o.w = f2bf(acc[i][6]) | (f2bf(acc[i][7]) << 16);
            *(uint4*)&Y[(size_t)row * ystrideU + ct * 4] = o;
        }
    }
}

// ===========================================================================
// Layer-1 gather, XCD column-split: blockIdx&1 selects a 64-col (128B) half;
// with round-robin blockIdx%8 -> XCD mapping, even XCDs only ever touch cols
// 0-63 and odd XCDs cols 64-127. Per-XCD L2 footprint of XW halves
// (25.6MB -> 12.8MB), so the structural L2-fill floor halves (8*25.6 ->
// 8*12.8 MB). One wave per (node, half); lanes 0-31 process even edges,
// lanes 32-63 odd edges (2 edges per 256B load); shfl_xor(32) combines.
// srcs/p/dinv loads stay scalar (wave-uniform addresses).
// ===========================================================================
__global__ __launch_bounds__(256) void k_gather128(const unsigned int* __restrict__ XW,
                                                   const int* __restrict__ p,
                                                   const int* __restrict__ srcs,
                                                   const float* __restrict__ dinv,
                                                   const float* __restrict__ b1,
                                                   unsigned int* __restrict__ H1b, int n) {
    const int half = blockIdx.x & 1;
    const int node =
        __builtin_amdgcn_readfirstlane((blockIdx.x >> 1) * 4 + (threadIdx.x >> 6));
    if (node >= n) return;
    const int tl = threadIdx.x & 31;
    const int hi = (threadIdx.x >> 5) & 1;
    const int start = (node == 0) ? 0 : p[node - 1];
    const int end = p[node];
    const float din = dinv[node];
    const unsigned int* XWh = XW + (half << 5);

    float a0 = 0.0f, a1 = 0.0f;
    int c = start;
    for (; c + 8 <= end; c += 8) {
        int s[8];
#pragma unroll
        for (int k = 0; k < 8; ++k) s[k] = __builtin_amdgcn_readfirstlane(srcs[c + k]);
        float w[8];
#pragma unroll
        for (int k = 0; k < 8; ++k) w[k] = dinv[s[k]];
        unsigned int u[4];
#pragma unroll
        for (int q = 0; q < 4; ++q) {
            const int sk = hi ? s[2 * q + 1] : s[2 * q];
            u[q] = XWh[((size_t)sk << 6) + tl];
        }
#pragma unroll
        for (int q = 0; q < 4; ++q) {
            const float wk = hi ? w[2 * q + 1] : w[2 * q];
            a0 = fmaf(bflo(u[q]), wk, a0);
            a1 = fmaf(bfhi(u[q]), wk, a1);
        }
    }
    for (; c + 2 <= end; c += 2) {
        const int s0 = __builtin_amdgcn_readfirstlane(srcs[c]);
        const int s1 = __builtin_amdgcn_readfirstlane(srcs[c + 1]);
        const float w0 = dinv[s0], w1 = dinv[s1];
        const int sk = hi ? s1 : s0;
        const float wk = hi ? w1 : w0;
        const unsigned int u = XWh[((size_t)sk << 6) + tl];
        a0 = fmaf(bflo(u), wk, a0);
        a1 = fmaf(bfhi(u), wk, a1);
    }
    if (c < end) {
        const int s0 = __builtin_amdgcn_readfirstlane(srcs[c]);
        const float wk = hi ? 0.0f : dinv[s0];
        const unsigned int u = XWh[((size_t)s0 << 6) + tl];
        a0 = fmaf(bflo(u), wk, a0);
        a1 = fmaf(bfhi(u), wk, a1);
    }
    a0 += __shfl_xor(a0, 32);
    a1 += __shfl_xor(a1, 32);

    const unsigned int us = XW[((size_t)node << 6) + (half << 5) + tl];
    a0 = fmaf(bflo(us), din, a0);
    a1 = fmaf(bfhi(us), din, a1);

    const int j = (half << 5) + tl;
    const float r0 = fmaxf(fmaf(a0, din, b1[2 * j]), 0.0f);
    const float r1 = fmaxf(fmaf(a1, din, b1[2 * j + 1]), 0.0f);
    if (hi == 0) H1b[((size_t)node << 6) + j] = f2bf(r0) | (f2bf(r1) << 16);
}

// ===========================================================================
// Layer-2 gather: one wave per node, 64 cols (128B rows = 1 L2 line), f32
// out. Scalar-pipe structure (wave-uniform srcs/dinv loads).
// ===========================================================================
__global__ __launch_bounds__(256) void k_gather64(const unsigned short* __restrict__ h2,
                                                  const int* __restrict__ p,
                                                  const int* __restrict__ srcs,
                                                  const float* __restrict__ dinv,
                                                  const float* __restrict__ b2,
                                                  float* __restrict__ out, int n) {
    const int node = __builtin_amdgcn_readfirstlane(blockIdx.x * 4 + (threadIdx.x >> 6));
    if (node >= n) return;
    const int t = threadIdx.x & 63;
    const int start = (node == 0) ? 0 : p[node - 1];
    const int end = p[node];
    const float din = dinv[node];
    float acc = bflo(h2[(size_t)node * 64 + t]) * din;

    int c = start;
    for (; c + 8 <= end; c += 8) {
        int s[8];
#pragma unroll
        for (int k = 0; k < 8; ++k) s[k] = __builtin_amdgcn_readfirstlane(srcs[c + k]);
        float w[8], v[8];
#pragma unroll
        for (int k = 0; k < 8; ++k) {
            w[k] = dinv[s[k]];
            v[k] = bflo(h2[((unsigned)s[k] << 6) + t]);
        }
#pragma unroll
        for (int k = 0; k < 8; ++k) acc = fmaf(v[k], w[k], acc);
    }
    for (; c < end; ++c) {
        const int s = __builtin_amdgcn_readfirstlane(srcs[c]);
        const float w = dinv[s];
        acc = fmaf(bflo(h2[((unsigned)s << 6) + t]), w, acc);
    }
    out[(size_t)node * 64 + t] = fmaf(acc, din, b2[t]);
}

// ===========================================================================
extern "C" void kernel_launch(void* const* d_in, const int* in_sizes, int n_in,
                              void* d_out, int out_size, void* d_ws, size_t ws_size,
                              hipStream_t stream) {
    const float* x  = (const float*)d_in[0];
    const int* ei   = (const int*)d_in[1];
    const float* W1 = (const float*)d_in[2];
    const float* b1 = (const float*)d_in[3];
    const float* W2 = (const float*)d_in[4];
    const float* b2 = (const float*)d_in[5];

    const int n = in_sizes[0] / 128;
    const int E = in_sizes[1] / 2;
    const int NB = (n + 127) >> 7;

    // ws layout: p[n] | dinv[n] | srcs[E] | XW[n*64 u32] | H1b[n*64 u32]
    // CSR-build temporaries alias into the H1b region (dead until gather128).
    auto al = [](size_t b) { return (b + 255) & ~(size_t)255; };
    const size_t off_p    = 0;
    const size_t off_dinv = off_p + al((size_t)n * 4);
    const size_t off_srcs = off_dinv + al((size_t)n * 4);
    const size_t off_XW   = off_srcs + al((size_t)E * 4);
    const size_t off_H1b  = off_XW + al((size_t)n * 64 * 4);
    const size_t need     = off_H1b + (size_t)n * 64 * 4;
    const size_t off_pk   = off_H1b;
    const size_t off_bc   = off_pk + al((size_t)E * 4);
    const size_t off_bb   = off_bc + al(1024 * 4);
    const size_t off_bu   = off_bb + al(1025 * 4);

    if (ws_size < need || NB > 1024) {
        hipMemsetAsync(d_out, 0, (size_t)out_size * 4, stream);
        return;
    }

    int*          p    = (int*)((char*)d_ws + off_p);
    float*        dinv = (float*)((char*)d_ws + off_dinv);
    int*          srcs = (int*)((char*)d_ws + off_srcs);
    unsigned int* XW   = (unsigned int*)((char*)d_ws + off_XW);
    unsigned int* H1b  = (unsigned int*)((char*)d_ws + off_H1b);
    unsigned int* pk   = (unsigned int*)((char*)d_ws + off_pk);
    int*          bCnt = (int*)((char*)d_ws + off_bc);
    int*          bBase= (int*)((char*)d_ws + off_bb);
    int*          bCur = (int*)((char*)d_ws + off_bu);
    float*        out  = (float*)d_out;

    const int gEdge = (E + 4095) / 4096;
    const int gG    = (n + 3) / 4;
    const int gG2   = gG * 2;  // (node-group, col-half) tasks

    // CSR build (bucket counting sort)
    hipMemsetAsync(bCnt, 0, 1024 * 4, stream);
    k_bktcount<<<gEdge, 256, 0, stream>>>(ei, bCnt, E, n);
    k_bktscan<<<1, 256, 0, stream>>>(bCnt, bBase, bCur, NB);
    k_bktscatter<<<gEdge, 256, 0, stream>>>(ei, bCur, pk, E, n);
    k_bktfill<<<NB, 256, 0, stream>>>(pk, bBase, p, dinv, srcs, n);

    // XW = bf16(x @ W1)
    k_gemm_rt<128, false><<<(n + 63) / 64, 256, 0, stream>>>(x, W1, XW, 64, n);

    // h1 = relu(gather(XW) + b1) -> H1b (bf16)
    k_gather128<<<gG2, 256, 0, stream>>>(XW, p, srcs, dinv, b1, H1b, n);

    // h2 = bf16(h1 @ W2) -> XW region (32 u32/row)
    k_gemm_rt<64, true><<<(n + 127) / 128, 256, 0, stream>>>(H1b, W2, XW, 32, n);

    // out = gather(h2) + b2 -> d_out (f32)
    k_gather64<<<gG, 256, 0, stream>>>((const unsigned short*)XW, p, srcs, dinv, b2, out, n);
}

// Round 3
// 351.022 us; speedup vs baseline: 2.1358x; 2.1358x over previous
//
#include <hip/hip_runtime.h>
#include <hip/hip_bf16.h>

#define DEVINL __device__ __forceinline__

DEVINL int clampidx(int v, int n) { return ((unsigned)v < (unsigned)n) ? v : 0; }
DEVINL float bflo(unsigned int u) { return __uint_as_float(u << 16); }
DEVINL float bfhi(unsigned int u) { return __uint_as_float(u & 0xffff0000u); }
// f32 -> bf16 round-to-nearest-even (finite inputs only)
DEVINL unsigned int f2bf(float f) {
    unsigned int u = __float_as_uint(f);
    u += 0x7fffu + ((u >> 16) & 1u);
    return u >> 16;
}

// ===========================================================================
// CSR build via bucket counting sort. Buckets = dst>>7 (128 nodes each).
// packed edge word: (dstLocal[7b] << 25) | src[25b]   (n < 2^25)
// ===========================================================================
__global__ __launch_bounds__(256) void k_bktscan(const int* __restrict__ bktCnt,
                                                 int* __restrict__ bktBase,
                                                 int* __restrict__ bktCur, int NB) {
    __shared__ int sh[256];
    int carry = 0;
    for (int c0 = 0; c0 < NB; c0 += 256) {
        const int i = c0 + threadIdx.x;
        const int v = (i < NB) ? bktCnt[i] : 0;
        sh[threadIdx.x] = v;
        __syncthreads();
        for (int off = 1; off < 256; off <<= 1) {
            int t = (threadIdx.x >= off) ? sh[threadIdx.x - off] : 0;
            __syncthreads();
            sh[threadIdx.x] += t;
            __syncthreads();
        }
        if (i < NB) {
            const int excl = carry + sh[threadIdx.x] - v;
            bktBase[i] = excl;
            bktCur[i] = excl;
        }
        const int tot = sh[255];
        __syncthreads();
        carry += tot;
    }
    if (threadIdx.x == 0) bktBase[NB] = carry;
}

__global__ __launch_bounds__(256) void k_bktscatter(const int* __restrict__ ei,
                                                    int* __restrict__ bktCur,
                                                    unsigned int* __restrict__ packed,
                                                    int E, int n) {
    __shared__ unsigned int sPack[4096];
    __shared__ unsigned short sBkt[4096];
    __shared__ int sHist[1024], sStart[1024], sLoc[1024];
    for (int i = threadIdx.x; i < 1024; i += 256) {
        sHist[i] = 0;
        sLoc[i] = 0;
    }
    __syncthreads();
    const int base = blockIdx.x * 4096;
#pragma unroll
    for (int j = 0; j < 16; ++j) {
        const int k = j * 256 + threadIdx.x;
        const int i = base + k;
        if (i < E) {
            const int s = clampidx(ei[i], n);
            const int d = clampidx(ei[(size_t)E + i], n);
            const int b = d >> 7;
            sPack[k] = ((unsigned)(d & 127) << 25) | (unsigned)s;
            sBkt[k] = (unsigned short)b;
            atomicAdd(&sHist[b], 1);
        }
    }
    __syncthreads();
    for (int b = threadIdx.x; b < 1024; b += 256) {
        const int c = sHist[b];
        sStart[b] = c ? atomicAdd(&bktCur[b], c) : 0;
    }
    __syncthreads();
#pragma unroll
    for (int j = 0; j < 16; ++j) {
        const int k = j * 256 + threadIdx.x;
        const int i = base + k;
        if (i < E) {
            const int b = sBkt[k];
            const int pos = sStart[b] + atomicAdd(&sLoc[b], 1);
            packed[pos] = sPack[k];
        }
    }
}

__global__ __launch_bounds__(256) void k_bktfill(const unsigned int* __restrict__ packed,
                                                 const int* __restrict__ bktBase,
                                                 int* __restrict__ p, float* __restrict__ dinv,
                                                 int* __restrict__ srcs, int n) {
    constexpr int CAP = 8192;
    __shared__ unsigned int sPack[CAP];
    __shared__ int sSrc[CAP];
    __shared__ int deg[128], incl[128], cur[128];
    const int bkt = blockIdx.x;
    const int e0 = bktBase[bkt], e1 = bktBase[bkt + 1];
    const int cnt = e1 - e0;
    const int tid = threadIdx.x;
    if (tid < 128) deg[tid] = 0;
    __syncthreads();
    for (int i = tid; i < cnt; i += 256) {
        const unsigned int u = packed[e0 + i];
        if (i < CAP) sPack[i] = u;
        atomicAdd(&deg[u >> 25], 1);
    }
    __syncthreads();
    if (tid < 128) incl[tid] = deg[tid];
    __syncthreads();
    for (int off = 1; off < 128; off <<= 1) {
        const int v = (tid < 128 && tid >= off) ? incl[tid - off] : 0;
        __syncthreads();
        if (tid < 128) incl[tid] += v;
        __syncthreads();
    }
    const int node0 = bkt << 7;
    if (tid < 128) {
        cur[tid] = incl[tid] - deg[tid];
        const int node = node0 + tid;
        if (node < n) {
            p[node] = e0 + incl[tid];
            dinv[node] = rsqrtf((float)deg[tid] + 1.0f);
        }
    }
    __syncthreads();
    for (int i = tid; i < cnt; i += 256) {
        const unsigned int u = (i < CAP) ? sPack[i] : packed[e0 + i];
        const int dl = (int)(u >> 25);
        const int s = (int)(u & 0x1FFFFFFu);
        const int pos = atomicAdd(&cur[dl], 1);
        if (pos < CAP) sSrc[pos] = s;
        else srcs[e0 + pos] = s;
    }
    __syncthreads();
    const int lim = cnt < CAP ? cnt : CAP;
    for (int i = tid; i < lim; i += 256) srcs[e0 + i] = sSrc[i];
}

// ===========================================================================
// Register-tiled GEMM body: Y(bf16 pairs)[n, BCOLS] = X[n,128] @ W[128, BCOLS]
// 256 threads; each computes a 4-row x 8-col register tile.
// ===========================================================================
template <int BCOLS, bool IN_BF16>
DEVINL void gemm_body(const void* __restrict__ Xv, const float* __restrict__ W,
                      unsigned int* __restrict__ Y, int ystrideU, int n, int blk,
                      float* Ws, float* xs) {
    constexpr int KC = 32;
    constexpr int CG = BCOLS / 8;
    constexpr int RG = 256 / CG;
    constexpr int BROWS = RG * 4;
    constexpr int P = BROWS + 4;

    const int tid = threadIdx.x;
    const int row0 = blk * BROWS;
    const int ct = tid % CG;
    const int rt = tid / CG;

    float acc[4][8];
#pragma unroll
    for (int i = 0; i < 4; ++i)
#pragma unroll
        for (int j = 0; j < 8; ++j) acc[i][j] = 0.0f;

    for (int k0 = 0; k0 < 128; k0 += KC) {
        __syncthreads();
        for (int idx = tid * 4; idx < KC * BCOLS; idx += 1024)
            *(float4*)&Ws[idx] = *(const float4*)&W[(size_t)k0 * BCOLS + idx];
        if (IN_BF16) {
            const int row = tid >> 1, q = tid & 1;
            const int grow = row0 + row;
            const unsigned int* src =
                (const unsigned int*)Xv + (size_t)grow * 64 + (k0 >> 1) + q * 8;
            uint4 u0 = make_uint4(0, 0, 0, 0), u1 = make_uint4(0, 0, 0, 0);
            if (grow < n) {
                u0 = *(const uint4*)src;
                u1 = *(const uint4*)(src + 4);
            }
            const int kb = q * 16;
            float* xp = &xs[row];
            xp[(kb + 0) * P] = bflo(u0.x); xp[(kb + 1) * P] = bfhi(u0.x);
            xp[(kb + 2) * P] = bflo(u0.y); xp[(kb + 3) * P] = bfhi(u0.y);
            xp[(kb + 4) * P] = bflo(u0.z); xp[(kb + 5) * P] = bfhi(u0.z);
            xp[(kb + 6) * P] = bflo(u0.w); xp[(kb + 7) * P] = bfhi(u0.w);
            xp[(kb + 8) * P] = bflo(u1.x); xp[(kb + 9) * P] = bfhi(u1.x);
            xp[(kb + 10) * P] = bflo(u1.y); xp[(kb + 11) * P] = bfhi(u1.y);
            xp[(kb + 12) * P] = bflo(u1.z); xp[(kb + 13) * P] = bfhi(u1.z);
            xp[(kb + 14) * P] = bflo(u1.w); xp[(kb + 15) * P] = bfhi(u1.w);
        } else {
            const int row = tid >> 2, q = tid & 3;
            const int grow = row0 + row;
            const float* src = (const float*)Xv + (size_t)grow * 128 + k0 + q * 8;
            float4 v0 = make_float4(0, 0, 0, 0), v1 = make_float4(0, 0, 0, 0);
            if (grow < n) {
                v0 = *(const float4*)src;
                v1 = *(const float4*)(src + 4);
            }
            const int kb = q * 8;
            float* xp = &xs[row];
            xp[(kb + 0) * P] = v0.x; xp[(kb + 1) * P] = v0.y;
            xp[(kb + 2) * P] = v0.z; xp[(kb + 3) * P] = v0.w;
            xp[(kb + 4) * P] = v1.x; xp[(kb + 5) * P] = v1.y;
            xp[(kb + 6) * P] = v1.z; xp[(kb + 7) * P] = v1.w;
        }
        __syncthreads();

#pragma unroll 8
        for (int k = 0; k < KC; ++k) {
            const float4 xv = *(const float4*)&xs[k * P + rt * 4];
            const float4 wA = *(const float4*)&Ws[k * BCOLS + ct * 8];
            const float4 wB = *(const float4*)&Ws[k * BCOLS + ct * 8 + 4];
            const float xr[4] = {xv.x, xv.y, xv.z, xv.w};
#pragma unroll
            for (int i = 0; i < 4; ++i) {
                acc[i][0] = fmaf(xr[i], wA.x, acc[i][0]);
                acc[i][1] = fmaf(xr[i], wA.y, acc[i][1]);
                acc[i][2] = fmaf(xr[i], wA.z, acc[i][2]);
                acc[i][3] = fmaf(xr[i], wA.w, acc[i][3]);
                acc[i][4] = fmaf(xr[i], wB.x, acc[i][4]);
                acc[i][5] = fmaf(xr[i], wB.y, acc[i][5]);
                acc[i][6] = fmaf(xr[i], wB.z, acc[i][6]);
                acc[i][7] = fmaf(xr[i], wB.w, acc[i][7]);
            }
        }
    }

#pragma unroll
    for (int i = 0; i < 4; ++i) {
        const int row = row0 + rt * 4 + i;
        if (row < n) {
            uint4 o;
            o.x = f2bf(acc[i][0]) | (f2bf(acc[i][1]) << 16);
            o.y = f2bf(acc[i][2]) | (f2bf(acc[i][3]) << 16);
            o.z = f2bf(acc[i][4]) | (f2bf(acc[i][5]) << 16);
            o.w = f2bf(acc[i][6]) | (f2bf(acc[i][7]) << 16);
            *(uint4*)&Y[(size_t)row * ystrideU + ct * 4] = o;
        }
    }
}

// Standalone GEMM for layer 2 (h1 bf16 @ W2 -> 64 cols).
__global__ __launch_bounds__(256) void k_gemm64(const void* __restrict__ Xv,
                                                const float* __restrict__ W,
                                                unsigned int* __restrict__ Y, int ystrideU,
                                                int n) {
    __shared__ float Ws[32 * 64];
    __shared__ float xs[32 * 132];
    gemm_body<64, true>(Xv, W, Y, ystrideU, n, blockIdx.x, Ws, xs);
}

// Fused: blocks [0, nCnt) run the CSR bucket-count pass; blocks [nCnt, ...)
// run the layer-1 GEMM. The two are independent; fusing removes one serial
// dispatch from the graph (single-stream capture = no inter-kernel overlap).
__global__ __launch_bounds__(256) void k_gemm128_count(const void* __restrict__ Xv,
                                                       const float* __restrict__ W,
                                                       unsigned int* __restrict__ Y, int n,
                                                       const int* __restrict__ ei,
                                                       int* __restrict__ bktCnt, int E,
                                                       int nCnt) {
    __shared__ float Ws[32 * 128];
    __shared__ float xs[32 * 68];
    if ((int)blockIdx.x < nCnt) {
        int* hist = (int*)Ws;  // reuse 4KB of the GEMM's LDS
        for (int i = threadIdx.x; i < 1024; i += 256) hist[i] = 0;
        __syncthreads();
        const int base = blockIdx.x * 4096;
#pragma unroll
        for (int j = 0; j < 16; ++j) {
            int i = base + j * 256 + threadIdx.x;
            if (i < E) atomicAdd(&hist[clampidx(ei[(size_t)E + i], n) >> 7], 1);
        }
        __syncthreads();
        for (int b = threadIdx.x; b < 1024; b += 256) {
            int c = hist[b];
            if (c) atomicAdd(&bktCnt[b], c);
        }
    } else {
        gemm_body<128, false>(Xv, W, Y, 64, n, (int)blockIdx.x - nCnt, Ws, xs);
    }
}

// ===========================================================================
// Layer-1 gather, scalar-pipe structure (proven round-1): one wave per node,
// 128 cols. node wave-uniform -> p/srcs/dinv loads scalarize (s_load
// broadcasts); per batch, 16 independent 256B row loads in flight (probe:
// 8 -> 16 outstanding misses to test parallelism- vs fabric-limit).
// Edge order (and hence fma order) identical to round 1 -> bit-identical.
// ===========================================================================
__global__ __launch_bounds__(256) void k_gather128(const unsigned int* __restrict__ XW,
                                                   const int* __restrict__ p,
                                                   const int* __restrict__ srcs,
                                                   const float* __restrict__ dinv,
                                                   const float* __restrict__ b1,
                                                   unsigned int* __restrict__ H1b, int n) {
    const int node = __builtin_amdgcn_readfirstlane(blockIdx.x * 4 + (threadIdx.x >> 6));
    if (node >= n) return;
    const int t = threadIdx.x & 63;
    const int start = (node == 0) ? 0 : p[node - 1];
    const int end = p[node];
    const float din = dinv[node];
    const unsigned int us = XW[(size_t)node * 64 + t];
    float a0 = bflo(us) * din, a1 = bfhi(us) * din;

    int c = start;
    for (; c + 16 <= end; c += 16) {
        int s[16];
#pragma unroll
        for (int k = 0; k < 16; ++k) s[k] = __builtin_amdgcn_readfirstlane(srcs[c + k]);
        float w[16];
        unsigned int u[16];
#pragma unroll
        for (int k = 0; k < 16; ++k) {
            w[k] = dinv[s[k]];
            u[k] = XW[((unsigned)s[k] << 6) + t];
        }
#pragma unroll
        for (int k = 0; k < 16; ++k) {
            a0 = fmaf(bflo(u[k]), w[k], a0);
            a1 = fmaf(bfhi(u[k]), w[k], a1);
        }
    }
    for (; c + 4 <= end; c += 4) {
        int s[4];
#pragma unroll
        for (int k = 0; k < 4; ++k) s[k] = __builtin_amdgcn_readfirstlane(srcs[c + k]);
        float w[4];
        unsigned int u[4];
#pragma unroll
        for (int k = 0; k < 4; ++k) {
            w[k] = dinv[s[k]];
            u[k] = XW[((unsigned)s[k] << 6) + t];
        }
#pragma unroll
        for (int k = 0; k < 4; ++k) {
            a0 = fmaf(bflo(u[k]), w[k], a0);
            a1 = fmaf(bfhi(u[k]), w[k], a1);
        }
    }
    for (; c < end; ++c) {
        const int s = __builtin_amdgcn_readfirstlane(srcs[c]);
        const float w = dinv[s];
        const unsigned int u = XW[((unsigned)s << 6) + t];
        a0 = fmaf(bflo(u), w, a0);
        a1 = fmaf(bfhi(u), w, a1);
    }
    const float r0 = fmaxf(fmaf(a0, din, b1[2 * t]), 0.0f);
    const float r1 = fmaxf(fmaf(a1, din, b1[2 * t + 1]), 0.0f);
    H1b[(size_t)node * 64 + t] = f2bf(r0) | (f2bf(r1) << 16);
}

// ===========================================================================
// Layer-2 gather, same scalar-pipe structure: one wave per node, 64 cols,
// f32 out.
// ===========================================================================
__global__ __launch_bounds__(256) void k_gather64(const unsigned short* __restrict__ h2,
                                                  const int* __restrict__ p,
                                                  const int* __restrict__ srcs,
                                                  const float* __restrict__ dinv,
                                                  const float* __restrict__ b2,
                                                  float* __restrict__ out, int n) {
    const int node = __builtin_amdgcn_readfirstlane(blockIdx.x * 4 + (threadIdx.x >> 6));
    if (node >= n) return;
    const int t = threadIdx.x & 63;
    const int start = (node == 0) ? 0 : p[node - 1];
    const int end = p[node];
    const float din = dinv[node];
    float acc = bflo(h2[(size_t)node * 64 + t]) * din;

    int c = start;
    for (; c + 16 <= end; c += 16) {
        int s[16];
#pragma unroll
        for (int k = 0; k < 16; ++k) s[k] = __builtin_amdgcn_readfirstlane(srcs[c + k]);
        float w[16], v[16];
#pragma unroll
        for (int k = 0; k < 16; ++k) {
            w[k] = dinv[s[k]];
            v[k] = bflo(h2[((unsigned)s[k] << 6) + t]);
        }
#pragma unroll
        for (int k = 0; k < 16; ++k) acc = fmaf(v[k], w[k], acc);
    }
    for (; c + 4 <= end; c += 4) {
        int s[4];
#pragma unroll
        for (int k = 0; k < 4; ++k) s[k] = __builtin_amdgcn_readfirstlane(srcs[c + k]);
        float w[4], v[4];
#pragma unroll
        for (int k = 0; k < 4; ++k) {
            w[k] = dinv[s[k]];
            v[k] = bflo(h2[((unsigned)s[k] << 6) + t]);
        }
#pragma unroll
        for (int k = 0; k < 4; ++k) acc = fmaf(v[k], w[k], acc);
    }
    for (; c < end; ++c) {
        const int s = __builtin_amdgcn_readfirstlane(srcs[c]);
        const float w = dinv[s];
        acc = fmaf(bflo(h2[((unsigned)s << 6) + t]), w, acc);
    }
    out[(size_t)node * 64 + t] = fmaf(acc, din, b2[t]);
}

// ===========================================================================
extern "C" void kernel_launch(void* const* d_in, const int* in_sizes, int n_in,
                              void* d_out, int out_size, void* d_ws, size_t ws_size,
                              hipStream_t stream) {
    const float* x  = (const float*)d_in[0];
    const int* ei   = (const int*)d_in[1];
    const float* W1 = (const float*)d_in[2];
    const float* b1 = (const float*)d_in[3];
    const float* W2 = (const float*)d_in[4];
    const float* b2 = (const float*)d_in[5];

    const int n = in_sizes[0] / 128;
    const int E = in_sizes[1] / 2;
    const int NB = (n + 127) >> 7;

    // ws layout: p[n] | dinv[n] | srcs[E] | XW[n*64 u32] | H1b[n*64 u32]
    // CSR-build temporaries alias into the H1b region (dead until gather128).
    auto al = [](size_t b) { return (b + 255) & ~(size_t)255; };
    const size_t off_p    = 0;
    const size_t off_dinv = off_p + al((size_t)n * 4);
    const size_t off_srcs = off_dinv + al((size_t)n * 4);
    const size_t off_XW   = off_srcs + al((size_t)E * 4);
    const size_t off_H1b  = off_XW + al((size_t)n * 64 * 4);
    const size_t need     = off_H1b + (size_t)n * 64 * 4;
    const size_t off_pk   = off_H1b;
    const size_t off_bc   = off_pk + al((size_t)E * 4);
    const size_t off_bb   = off_bc + al(1024 * 4);
    const size_t off_bu   = off_bb + al(1025 * 4);

    if (ws_size < need || NB > 1024) {
        hipMemsetAsync(d_out, 0, (size_t)out_size * 4, stream);
        return;
    }

    int*          p    = (int*)((char*)d_ws + off_p);
    float*        dinv = (float*)((char*)d_ws + off_dinv);
    int*          srcs = (int*)((char*)d_ws + off_srcs);
    unsigned int* XW   = (unsigned int*)((char*)d_ws + off_XW);
    unsigned int* H1b  = (unsigned int*)((char*)d_ws + off_H1b);
    unsigned int* pk   = (unsigned int*)((char*)d_ws + off_pk);
    int*          bCnt = (int*)((char*)d_ws + off_bc);
    int*          bBase= (int*)((char*)d_ws + off_bb);
    int*          bCur = (int*)((char*)d_ws + off_bu);
    float*        out  = (float*)d_out;

    const int gEdge = (E + 4095) / 4096;
    const int gGemm = (n + 63) / 64;
    const int gG    = (n + 3) / 4;

    // Fused: CSR bucket-count (blocks [0,gEdge)) + XW = bf16(x @ W1)
    hipMemsetAsync(bCnt, 0, 1024 * 4, stream);
    k_gemm128_count<<<gEdge + gGemm, 256, 0, stream>>>(x, W1, XW, n, ei, bCnt, E, gEdge);

    // CSR build (bucket counting sort)
    k_bktscan<<<1, 256, 0, stream>>>(bCnt, bBase, bCur, NB);
    k_bktscatter<<<gEdge, 256, 0, stream>>>(ei, bCur, pk, E, n);
    k_bktfill<<<NB, 256, 0, stream>>>(pk, bBase, p, dinv, srcs, n);

    // h1 = relu(gather(XW) + b1) -> H1b (bf16)
    k_gather128<<<gG, 256, 0, stream>>>(XW, p, srcs, dinv, b1, H1b, n);

    // h2 = bf16(h1 @ W2) -> XW region (32 u32/row)
    k_gemm64<<<(n + 127) / 128, 256, 0, stream>>>(H1b, W2, XW, 32, n);

    // out = gather(h2) + b2 -> d_out (f32)
    k_gather64<<<gG, 256, 0, stream>>>((const unsigned short*)XW, p, srcs, dinv, b2, out, n);
}